// Round 1
// baseline (922.404 us; speedup 1.0000x reference)
//
#include <hip/hip_runtime.h>

// UniformShardedEmbeddingBags: per-table embedding bag, sum pooling.
// weights: [E=200000, T=16, D=64] fp32 (row (e,t) is 256 B contiguous, 256 B aligned)
// indices: [B=4096, T=16, L=20] int
// out:     [B, T, D] fp32
//
// Layout choice: 16 lanes per bag, each lane owns a float4 (4 of the D=64 floats).
// One wave = 4 bags; each gather instruction moves 4 x 256 B = 1 KiB.

constexpr int E = 200000;
constexpr int T = 16;
constexpr int D = 64;
constexpr int B = 4096;
constexpr int L = 20;

__global__ __launch_bounds__(256) void embed_bag_kernel(
    const float* __restrict__ w,      // [E, T, D]
    const int* __restrict__ idx,      // [B, T, L]
    float* __restrict__ out)          // [B, T, D]
{
    const int tid = blockIdx.x * blockDim.x + threadIdx.x;
    const int bag = tid >> 4;         // global bag id in [0, B*T)
    const int sub = tid & 15;         // which float4 of the D=64 row
    if (bag >= B * T) return;

    const int t = bag & (T - 1);      // table id (bag = b*T + t)
    const int* bag_idx = idx + (long long)bag * L;

    // Per-lane constant byte offset within a weights "super-row" of e:
    // float offset = t*D + sub*4 ; element stride per e = T*D = 1024 floats.
    const long long lane_off = (long long)t * D + sub * 4;

    float4 acc = make_float4(0.f, 0.f, 0.f, 0.f);
#pragma unroll
    for (int l = 0; l < L; ++l) {
        const int e = bag_idx[l];     // wave-group broadcast load
        const float4 v = *(const float4*)(w + (long long)e * (T * D) + lane_off);
        acc.x += v.x; acc.y += v.y; acc.z += v.z; acc.w += v.w;
    }

    *(float4*)(out + (long long)bag * D + sub * 4) = acc;
}

extern "C" void kernel_launch(void* const* d_in, const int* in_sizes, int n_in,
                              void* d_out, int out_size, void* d_ws, size_t ws_size,
                              hipStream_t stream) {
    const float* w = (const float*)d_in[0];
    const int* idx = (const int*)d_in[1];
    float* out = (float*)d_out;

    const int total_threads = B * T * 16;          // 16 lanes per bag
    const int block = 256;
    const int grid = (total_threads + block - 1) / block;  // 4096
    embed_bag_kernel<<<grid, block, 0, stream>>>(w, idx, out);
}